// Round 1
// baseline (273.394 us; speedup 1.0000x reference)
//
#include <hip/hip_runtime.h>
#include <hip/hip_bf16.h>
#include <stdint.h>

typedef unsigned short u16;
typedef __bf16 v8bf __attribute__((ext_vector_type(8)));
typedef float  v4f  __attribute__((ext_vector_type(4)));

#define N_ROWS 8192
#define C_REAL 10000
#define C_PAD  10112   /* 79 * 128 */
#define D_DIM  512
#define BM 128
#define BN 128
#define BK 64

__device__ __forceinline__ unsigned pack2bf(float a, float b) {
    unsigned short ua = __builtin_bit_cast(unsigned short, (__bf16)a);
    unsigned short ub = __builtin_bit_cast(unsigned short, (__bf16)b);
    return (unsigned)ua | ((unsigned)ub << 16);
}

// One wave per row: L2-normalize, write bf16 row + f32 sum-of-squares-of-normalized.
// Rows >= nreal are padding: bf16 zeros, o2 = 1e30 (=> dis = -5e30 => exp = 0).
__global__ __launch_bounds__(256) void norm_rows_kernel(
    const float* __restrict__ x, u16* __restrict__ ob, float* __restrict__ o2,
    int nreal, int ntotal)
{
    int row  = blockIdx.x * 4 + (threadIdx.x >> 6);
    int lane = threadIdx.x & 63;
    if (row >= ntotal) return;
    uint2* orow = (uint2*)(ob + (size_t)row * D_DIM);
    if (row >= nreal) {
        uint2 z; z.x = 0u; z.y = 0u;
        orow[lane] = z; orow[64 + lane] = z;
        if (lane == 0) o2[row] = 1e30f;
        return;
    }
    const float4* xr = (const float4*)(x + (size_t)row * D_DIM);
    float4 v0 = xr[lane];
    float4 v1 = xr[64 + lane];
    float s = v0.x*v0.x + v0.y*v0.y + v0.z*v0.z + v0.w*v0.w
            + v1.x*v1.x + v1.y*v1.y + v1.z*v1.z + v1.w*v1.w;
    #pragma unroll
    for (int m = 1; m < 64; m <<= 1) s += __shfl_xor(s, m, 64);
    float nrm = sqrtf(s);
    float inv = 1.0f / fmaxf(nrm, 1e-12f);
    if (lane == 0) o2[row] = s * inv * inv;
    uint2 p0, p1;
    p0.x = pack2bf(v0.x * inv, v0.y * inv);
    p0.y = pack2bf(v0.z * inv, v0.w * inv);
    p1.x = pack2bf(v1.x * inv, v1.y * inv);
    p1.y = pack2bf(v1.z * inv, v1.w * inv);
    orow[lane]      = p0;
    orow[64 + lane] = p1;
}

// Exact (f32) positive-class distance: one wave per row, gathered center row.
__global__ __launch_bounds__(256) void pos_exact_kernel(
    const float* __restrict__ feat, const float* __restrict__ cent,
    const int* __restrict__ labels, float* __restrict__ pose)
{
    int row  = blockIdx.x * 4 + (threadIdx.x >> 6);
    int lane = threadIdx.x & 63;
    int lab  = labels[row];
    const float4* fr = (const float4*)(feat + (size_t)row * D_DIM);
    const float4* cr = (const float4*)(cent + (size_t)lab * D_DIM);
    float sf = 0.f, sc = 0.f, sd = 0.f;
    #pragma unroll
    for (int i = 0; i < 2; ++i) {
        float4 a = fr[i * 64 + lane];
        float4 b = cr[i * 64 + lane];
        sf += a.x*a.x + a.y*a.y + a.z*a.z + a.w*a.w;
        sc += b.x*b.x + b.y*b.y + b.z*b.z + b.w*b.w;
        sd += a.x*b.x + a.y*b.y + a.z*b.z + a.w*b.w;
    }
    #pragma unroll
    for (int m = 1; m < 64; m <<= 1) {
        sf += __shfl_xor(sf, m, 64);
        sc += __shfl_xor(sc, m, 64);
        sd += __shfl_xor(sd, m, 64);
    }
    if (lane == 0) {
        float nf = fmaxf(sqrtf(sf), 1e-12f);
        float nc = fmaxf(sqrtf(sc), 1e-12f);
        float invf = 1.f / nf, invc = 1.f / nc;
        float f2n = sf * invf * invf;
        float c2n = sc * invc * invc;
        float dtn = sd * invf * invc;
        pose[row] = -5.0f * (f2n + c2n - 2.0f * dtn);
    }
}

// Fused bf16 MFMA GEMM (A[N,D] * B[C,D]^T) + exp-epilogue:
// accumulates per-row sum(exp(dis)) via atomics, captures dis at label column.
__global__ __launch_bounds__(256) void gemm_kernel(
    const u16* __restrict__ A, const u16* __restrict__ B,
    const float* __restrict__ f2, const float* __restrict__ c2,
    const int* __restrict__ labels,
    float* __restrict__ rowsum, float* __restrict__ posdis)
{
    __shared__ __align__(16) u16 As[BM * BK];   // 16 KB, XOR-swizzled 16B chunks
    __shared__ __align__(16) u16 Bs[BN * BK];   // 16 KB
    __shared__ float f2s[BM];
    __shared__ float c2s[BN];
    __shared__ int   labs[BM];

    const int rowBase = blockIdx.y * BM;
    const int colBase = blockIdx.x * BN;
    const int t    = threadIdx.x;
    const int lane = t & 63;
    const int w    = t >> 6;
    const int wr   = w >> 1, wc = w & 1;

    if (t < BM) { f2s[t] = f2[rowBase + t]; labs[t] = labels[rowBase + t]; }
    else        { c2s[t - BM] = c2[colBase + (t - BM)]; }

    v4f acc[4][4];
    #pragma unroll
    for (int m = 0; m < 4; ++m)
        #pragma unroll
        for (int n = 0; n < 4; ++n) acc[m][n] = (v4f){0.f, 0.f, 0.f, 0.f};

    for (int kt = 0; kt < D_DIM / BK; ++kt) {
        const int k0 = kt * BK;
        // Stage A and B tiles: global_load_lds width 16, pre-swizzled source so
        // LDS physical chunk (r, pc) holds logical chunk (r, pc ^ (r&7)).
        #pragma unroll
        for (int i = 0; i < 4; ++i) {
            int chunk = i * 256 + t;          // 16B-chunk index, 8 chunks per row
            int r  = chunk >> 3;
            int pc = chunk & 7;
            int lc = pc ^ (r & 7);
            const u16* ga = A + (size_t)(rowBase + r) * D_DIM + k0 + lc * 8;
            __builtin_amdgcn_global_load_lds(
                (const __attribute__((address_space(1))) void*)ga,
                (__attribute__((address_space(3))) void*)(As + chunk * 8), 16, 0, 0);
            const u16* gb = B + (size_t)(colBase + r) * D_DIM + k0 + lc * 8;
            __builtin_amdgcn_global_load_lds(
                (const __attribute__((address_space(1))) void*)gb,
                (__attribute__((address_space(3))) void*)(Bs + chunk * 8), 16, 0, 0);
        }
        __syncthreads();
        #pragma unroll
        for (int ks = 0; ks < 2; ++ks) {
            v8bf aF[4], bF[4];
            #pragma unroll
            for (int m = 0; m < 4; ++m) {
                int ra = wr * 64 + m * 16 + (lane & 15);
                int ca = (ks * 4 + (lane >> 4)) ^ (ra & 7);
                aF[m] = *(const v8bf*)((const char*)As + ra * 128 + ca * 16);
                int rb = wc * 64 + m * 16 + (lane & 15);
                int cb = (ks * 4 + (lane >> 4)) ^ (rb & 7);
                bF[m] = *(const v8bf*)((const char*)Bs + rb * 128 + cb * 16);
            }
            #pragma unroll
            for (int m = 0; m < 4; ++m)
                #pragma unroll
                for (int n = 0; n < 4; ++n)
                    acc[m][n] = __builtin_amdgcn_mfma_f32_16x16x32_bf16(
                        aF[m], bF[n], acc[m][n], 0, 0, 0);
        }
        __syncthreads();
    }

    // Epilogue: dis = -5*(f2 + c2 - 2*dot); exp; per-row sums; label capture.
    const int c15 = lane & 15, h = lane >> 4;
    #pragma unroll
    for (int m = 0; m < 4; ++m) {
        float s[4] = {0.f, 0.f, 0.f, 0.f};
        const int lr0 = wr * 64 + m * 16 + h * 4;
        #pragma unroll
        for (int n = 0; n < 4; ++n) {
            int lcol = wc * 64 + n * 16 + c15;
            int gcol = colBase + lcol;
            float cc = c2s[lcol];
            #pragma unroll
            for (int j = 0; j < 4; ++j) {
                int lr = lr0 + j;
                float dis = -5.0f * (f2s[lr] + cc - 2.0f * acc[m][n][j]);
                float e = __expf(dis);
                s[j] += e;
                if (labs[lr] == gcol) posdis[rowBase + lr] = dis;
            }
        }
        #pragma unroll
        for (int msk = 1; msk < 16; msk <<= 1)
            #pragma unroll
            for (int j = 0; j < 4; ++j) s[j] += __shfl_xor(s[j], msk, 64);
        if (c15 == 0) {
            #pragma unroll
            for (int j = 0; j < 4; ++j)
                atomicAdd(&rowsum[rowBase + lr0 + j], s[j]);
        }
    }
}

// Final scalar reduction: loss and unbiased variance (f64 accumulation).
__global__ __launch_bounds__(256) void finalize_kernel(
    const float* __restrict__ posdis, const float* __restrict__ pose,
    const float* __restrict__ rowsum, const int* __restrict__ labels,
    const float* __restrict__ bias, float* __restrict__ out)
{
    int t = threadIdx.x;
    double sl = 0.0, sp = 0.0, sp2 = 0.0;
    for (int r = t; r < N_ROWS; r += 256) {
        float pd = posdis[r];                 // bf16-path label term (matches rowsum)
        float p  = pose[r] + bias[labels[r]]; // exact-path pos_metric
        float num = __expf(p);
        float den = rowsum[r] - __expf(pd) + num;
        sl  += (double)(logf(den) - p);
        sp  += (double)p;
        sp2 += (double)p * (double)p;
    }
    #pragma unroll
    for (int m = 1; m < 64; m <<= 1) {
        sl  += __shfl_xor(sl,  m, 64);
        sp  += __shfl_xor(sp,  m, 64);
        sp2 += __shfl_xor(sp2, m, 64);
    }
    __shared__ double sh[3][4];
    int w = t >> 6, lane = t & 63;
    if (lane == 0) { sh[0][w] = sl; sh[1][w] = sp; sh[2][w] = sp2; }
    __syncthreads();
    if (t == 0) {
        sl  = sh[0][0] + sh[0][1] + sh[0][2] + sh[0][3];
        sp  = sh[1][0] + sh[1][1] + sh[1][2] + sh[1][3];
        sp2 = sh[2][0] + sh[2][1] + sh[2][2] + sh[2][3];
        const double N = (double)N_ROWS;
        double mean = sp / N;
        double var  = (sp2 - N * mean * mean) / (N - 1.0);
        double loss = sl / N + var;
        out[0] = (float)loss;
        out[1] = (float)var;
    }
}

extern "C" void kernel_launch(void* const* d_in, const int* in_sizes, int n_in,
                              void* d_out, int out_size, void* d_ws, size_t ws_size,
                              hipStream_t stream) {
    const float* features = (const float*)d_in[0];
    const int*   labels   = (const int*)d_in[1];
    const float* centers  = (const float*)d_in[2];
    const float* bias     = (const float*)d_in[3];
    float* out = (float*)d_out;
    char* ws = (char*)d_ws;

    // Workspace layout (all 16B aligned), ~18.9 MB total.
    u16*   fb     = (u16*)(ws);                                    // 8192*512*2
    u16*   cb     = (u16*)(ws + 8388608);                          // 10112*512*2
    float* f2     = (float*)(ws + 18743296);                       // 8192*4
    float* c2     = (float*)(ws + 18776064);                       // 10112*4
    float* rowsum = (float*)(ws + 18816512);                       // 8192*4
    float* posdis = (float*)(ws + 18849280);                       // 8192*4
    float* pose   = (float*)(ws + 18882048);                       // 8192*4

    hipMemsetAsync(rowsum, 0, N_ROWS * sizeof(float), stream);

    hipLaunchKernelGGL(norm_rows_kernel, dim3(N_ROWS / 4), dim3(256), 0, stream,
                       features, fb, f2, N_ROWS, N_ROWS);
    hipLaunchKernelGGL(norm_rows_kernel, dim3(C_PAD / 4), dim3(256), 0, stream,
                       centers, cb, c2, C_REAL, C_PAD);
    hipLaunchKernelGGL(pos_exact_kernel, dim3(N_ROWS / 4), dim3(256), 0, stream,
                       features, centers, labels, pose);
    hipLaunchKernelGGL(gemm_kernel, dim3(C_PAD / BN, N_ROWS / BM), dim3(256), 0, stream,
                       fb, cb, f2, c2, labels, rowsum, posdis);
    hipLaunchKernelGGL(finalize_kernel, dim3(1), dim3(256), 0, stream,
                       posdis, pose, rowsum, labels, bias, out);
}

// Round 2
// 221.848 us; speedup vs baseline: 1.2323x; 1.2323x over previous
//
#include <hip/hip_runtime.h>
#include <hip/hip_bf16.h>
#include <stdint.h>

typedef unsigned short u16;
typedef __bf16 v8bf __attribute__((ext_vector_type(8)));
typedef float  v4f  __attribute__((ext_vector_type(4)));

#define N_ROWS 8192
#define C_REAL 10000
#define C_PAD  10240   /* 40 * 256 */
#define D_DIM  512
#define BM 256
#define BN 256
#define BK 64
#define KTILES (D_DIM / BK)   /* 8 */

/* LDS map (bytes): buf0 @0, buf1 @65536; within a buf:
   A-half0 @0, A-half1 @16384, B-half0 @32768, B-half1 @49152.
   f2s @131072, c2s @132096, labs @133120. */
#define SM_BUF   65536
#define SM_HALF  16384
#define SM_BOFF  32768
#define SM_F2   131072
#define SM_C2   132096
#define SM_LAB  133120
#define SM_TOTAL 134144
static_assert(SM_TOTAL <= 160 * 1024, "LDS budget");

#define BARRIER() do { asm volatile("" ::: "memory"); \
                       __builtin_amdgcn_s_barrier();  \
                       asm volatile("" ::: "memory"); } while (0)
#define MFMA(d, a, b) d = __builtin_amdgcn_mfma_f32_16x16x32_bf16(a, b, d, 0, 0, 0)

__device__ __forceinline__ unsigned pack2bf(float a, float b) {
    unsigned short ua = __builtin_bit_cast(unsigned short, (__bf16)a);
    unsigned short ub = __builtin_bit_cast(unsigned short, (__bf16)b);
    return (unsigned)ua | ((unsigned)ub << 16);
}

// One wave per row: L2-normalize, write bf16 row + f32 sum-of-squares-of-normalized.
// Rows >= nreal are padding: bf16 zeros, o2 = 1e30 (=> dis = -5e30 => exp = 0).
__global__ __launch_bounds__(256) void norm_rows_kernel(
    const float* __restrict__ x, u16* __restrict__ ob, float* __restrict__ o2,
    int nreal, int ntotal)
{
    int row  = blockIdx.x * 4 + (threadIdx.x >> 6);
    int lane = threadIdx.x & 63;
    if (row >= ntotal) return;
    uint2* orow = (uint2*)(ob + (size_t)row * D_DIM);
    if (row >= nreal) {
        uint2 z; z.x = 0u; z.y = 0u;
        orow[lane] = z; orow[64 + lane] = z;
        if (lane == 0) o2[row] = 1e30f;
        return;
    }
    const float4* xr = (const float4*)(x + (size_t)row * D_DIM);
    float4 v0 = xr[lane];
    float4 v1 = xr[64 + lane];
    float s = v0.x*v0.x + v0.y*v0.y + v0.z*v0.z + v0.w*v0.w
            + v1.x*v1.x + v1.y*v1.y + v1.z*v1.z + v1.w*v1.w;
    #pragma unroll
    for (int m = 1; m < 64; m <<= 1) s += __shfl_xor(s, m, 64);
    float nrm = sqrtf(s);
    float inv = 1.0f / fmaxf(nrm, 1e-12f);
    if (lane == 0) o2[row] = s * inv * inv;
    uint2 p0, p1;
    p0.x = pack2bf(v0.x * inv, v0.y * inv);
    p0.y = pack2bf(v0.z * inv, v0.w * inv);
    p1.x = pack2bf(v1.x * inv, v1.y * inv);
    p1.y = pack2bf(v1.z * inv, v1.w * inv);
    orow[lane]      = p0;
    orow[64 + lane] = p1;
}

// Exact (f32) positive-class distance: one wave per row, gathered center row.
__global__ __launch_bounds__(256) void pos_exact_kernel(
    const float* __restrict__ feat, const float* __restrict__ cent,
    const int* __restrict__ labels, float* __restrict__ pose)
{
    int row  = blockIdx.x * 4 + (threadIdx.x >> 6);
    int lane = threadIdx.x & 63;
    int lab  = labels[row];
    const float4* fr = (const float4*)(feat + (size_t)row * D_DIM);
    const float4* cr = (const float4*)(cent + (size_t)lab * D_DIM);
    float sf = 0.f, sc = 0.f, sd = 0.f;
    #pragma unroll
    for (int i = 0; i < 2; ++i) {
        float4 a = fr[i * 64 + lane];
        float4 b = cr[i * 64 + lane];
        sf += a.x*a.x + a.y*a.y + a.z*a.z + a.w*a.w;
        sc += b.x*b.x + b.y*b.y + b.z*b.z + b.w*b.w;
        sd += a.x*b.x + a.y*b.y + a.z*b.z + a.w*b.w;
    }
    #pragma unroll
    for (int m = 1; m < 64; m <<= 1) {
        sf += __shfl_xor(sf, m, 64);
        sc += __shfl_xor(sc, m, 64);
        sd += __shfl_xor(sd, m, 64);
    }
    if (lane == 0) {
        float nf = fmaxf(sqrtf(sf), 1e-12f);
        float nc = fmaxf(sqrtf(sc), 1e-12f);
        float invf = 1.f / nf, invc = 1.f / nc;
        float f2n = sf * invf * invf;
        float c2n = sc * invc * invc;
        float dtn = sd * invf * invc;
        pose[row] = -5.0f * (f2n + c2n - 2.0f * dtn);
    }
}

// 256x256x(BK=64) 8-wave MFMA GEMM, 4-phase-per-K-tile pipelined schedule
// (counted-vmcnt double buffer), fused exp epilogue.
__global__ __launch_bounds__(512, 2) void gemm_kernel(
    const u16* __restrict__ A, const u16* __restrict__ B,
    const float* __restrict__ f2, const float* __restrict__ c2,
    const int* __restrict__ labels,
    float* __restrict__ rowsum, float* __restrict__ posdis)
{
    extern __shared__ char sm[];
    const int rowBase = blockIdx.y * BM;
    const int colBase = blockIdx.x * BN;
    const int tid  = threadIdx.x;
    const int lane = tid & 63;
    const int w    = tid >> 6;
    const int wr   = w >> 2;        // 0..1 : 128-row group
    const int wc   = w & 3;         // 0..3 : 64-col group
    const int l15  = lane & 15;
    const int h4   = lane >> 4;
    const int xorv = l15 & 7;
    const int bRow0 = (wc & 1) * 64;

    // Stage one K-tile (A 256x64 + B 256x64, both-sides-swizzled, 8 loads/thread).
    auto stage_tile = [&](int kt, char* dst) {
        const int k0 = kt * BK;
        #pragma unroll
        for (int i = 0; i < 2; ++i) {
            const int c  = i * 512 + tid;       // 16B chunk id within a half
            const int r  = c >> 3;              // row 0..127 within half
            const int lc = (c & 7) ^ (r & 7);   // logical chunk for physical slot
            const size_t goff = (size_t)r * D_DIM + k0 + lc * 8;
            __builtin_amdgcn_global_load_lds(
                (const __attribute__((address_space(1))) void*)(A + (size_t)rowBase * D_DIM + goff),
                (__attribute__((address_space(3))) void*)(dst + c * 16), 16, 0, 0);
            __builtin_amdgcn_global_load_lds(
                (const __attribute__((address_space(1))) void*)(A + (size_t)(rowBase + 128) * D_DIM + goff),
                (__attribute__((address_space(3))) void*)(dst + SM_HALF + c * 16), 16, 0, 0);
            __builtin_amdgcn_global_load_lds(
                (const __attribute__((address_space(1))) void*)(B + (size_t)colBase * D_DIM + goff),
                (__attribute__((address_space(3))) void*)(dst + SM_BOFF + c * 16), 16, 0, 0);
            __builtin_amdgcn_global_load_lds(
                (const __attribute__((address_space(1))) void*)(B + (size_t)(colBase + 128) * D_DIM + goff),
                (__attribute__((address_space(3))) void*)(dst + SM_BOFF + SM_HALF + c * 16), 16, 0, 0);
        }
    };

    // Prologue: epilogue tables + tile 0; full drain via __syncthreads.
    if (tid < 256) {
        ((float*)(sm + SM_F2))[tid] = f2[rowBase + tid];
        ((int*)(sm + SM_LAB))[tid]  = labels[rowBase + tid];
    } else {
        ((float*)(sm + SM_C2))[tid - 256] = c2[colBase + (tid - 256)];
    }
    stage_tile(0, sm);
    __syncthreads();

    v4f acc[8][4];
    #pragma unroll
    for (int m = 0; m < 8; ++m)
        #pragma unroll
        for (int n = 0; n < 4; ++n) acc[m][n] = (v4f){0.f, 0.f, 0.f, 0.f};

    v8bf aF[4][2], bFa[2][2], bFb[2][2];

    for (int t = 0; t < KTILES; ++t) {
        const char* bufc = sm + (t & 1) * SM_BUF;
        char*       bufn = sm + ((t + 1) & 1) * SM_BUF;
        const char* aBase = bufc + wr * SM_HALF;
        const char* bBase = bufc + SM_BOFF + (wc >> 1) * SM_HALF;

        // ---- phase 0: read aF(mh0) + bFa(n0,1); stage tile t+1 ----
        #pragma unroll
        for (int m = 0; m < 4; ++m)
            #pragma unroll
            for (int ks = 0; ks < 2; ++ks) {
                const int ra = m * 16 + l15;
                aF[m][ks] = *(const v8bf*)(aBase + ra * 128 + ((((ks << 2) + h4) ^ xorv) << 4));
            }
        #pragma unroll
        for (int n = 0; n < 2; ++n)
            #pragma unroll
            for (int ks = 0; ks < 2; ++ks) {
                const int rb = bRow0 + n * 16 + l15;
                bFa[n][ks] = *(const v8bf*)(bBase + rb * 128 + ((((ks << 2) + h4) ^ xorv) << 4));
            }
        if (t + 1 < KTILES) stage_tile(t + 1, bufn);
        BARRIER();
        __builtin_amdgcn_s_setprio(1);
        #pragma unroll
        for (int m = 0; m < 4; ++m)
            #pragma unroll
            for (int n = 0; n < 2; ++n) {
                MFMA(acc[m][n], aF[m][0], bFa[n][0]);
                MFMA(acc[m][n], aF[m][1], bFa[n][1]);
            }
        __builtin_amdgcn_s_setprio(0);
        BARRIER();

        // ---- phase 1: read bFb(n2,3); MFMA mh0 x n2,3 ----
        #pragma unroll
        for (int n = 0; n < 2; ++n)
            #pragma unroll
            for (int ks = 0; ks < 2; ++ks) {
                const int rb = bRow0 + (n + 2) * 16 + l15;
                bFb[n][ks] = *(const v8bf*)(bBase + rb * 128 + ((((ks << 2) + h4) ^ xorv) << 4));
            }
        BARRIER();
        __builtin_amdgcn_s_setprio(1);
        #pragma unroll
        for (int m = 0; m < 4; ++m)
            #pragma unroll
            for (int n = 0; n < 2; ++n) {
                MFMA(acc[m][n + 2], aF[m][0], bFb[n][0]);
                MFMA(acc[m][n + 2], aF[m][1], bFb[n][1]);
            }
        __builtin_amdgcn_s_setprio(0);
        BARRIER();

        // ---- phase 2: read aF(mh1); MFMA mh1 x n2,3 ----
        #pragma unroll
        for (int m = 0; m < 4; ++m)
            #pragma unroll
            for (int ks = 0; ks < 2; ++ks) {
                const int ra = 64 + m * 16 + l15;
                aF[m][ks] = *(const v8bf*)(aBase + ra * 128 + ((((ks << 2) + h4) ^ xorv) << 4));
            }
        BARRIER();
        __builtin_amdgcn_s_setprio(1);
        #pragma unroll
        for (int m = 0; m < 4; ++m)
            #pragma unroll
            for (int n = 0; n < 2; ++n) {
                MFMA(acc[m + 4][n + 2], aF[m][0], bFb[n][0]);
                MFMA(acc[m + 4][n + 2], aF[m][1], bFb[n][1]);
            }
        __builtin_amdgcn_s_setprio(0);
        BARRIER();

        // ---- phase 3: MFMA mh1 x n0,1 (no reads); counted wait for next tile ----
        __builtin_amdgcn_s_setprio(1);
        #pragma unroll
        for (int m = 0; m < 4; ++m)
            #pragma unroll
            for (int n = 0; n < 2; ++n) {
                MFMA(acc[m + 4][n], aF[m][0], bFa[n][0]);
                MFMA(acc[m + 4][n], aF[m][1], bFa[n][1]);
            }
        __builtin_amdgcn_s_setprio(0);
        if (t + 1 < KTILES) asm volatile("s_waitcnt vmcnt(0)" ::: "memory");
        BARRIER();
    }

    // Epilogue: dis = -5*(f2 + c2 - 2*dot); exp; per-row sums; label capture.
    const float* f2s  = (const float*)(sm + SM_F2);
    const float* c2s  = (const float*)(sm + SM_C2);
    const int*   labs = (const int*)(sm + SM_LAB);
    #pragma unroll
    for (int m = 0; m < 8; ++m) {
        float s[4] = {0.f, 0.f, 0.f, 0.f};
        const int lr0 = wr * 128 + m * 16 + h4 * 4;
        #pragma unroll
        for (int n = 0; n < 4; ++n) {
            const int lcol = wc * 64 + n * 16 + l15;
            const int gcol = colBase + lcol;
            const float cc = c2s[lcol];
            #pragma unroll
            for (int j = 0; j < 4; ++j) {
                const int lr = lr0 + j;
                float dis = -5.0f * (f2s[lr] + cc - 2.0f * acc[m][n][j]);
                float e = __expf(dis);
                s[j] += e;
                if (labs[lr] == gcol) posdis[rowBase + lr] = dis;
            }
        }
        #pragma unroll
        for (int msk = 1; msk < 16; msk <<= 1) {
            #pragma unroll
            for (int j = 0; j < 4; ++j) s[j] += __shfl_xor(s[j], msk, 64);
        }
        if (l15 == 0) {
            #pragma unroll
            for (int j = 0; j < 4; ++j)
                atomicAdd(&rowsum[rowBase + lr0 + j], s[j]);
        }
    }
}

// Final scalar reduction: loss and unbiased variance (f64 accumulation).
__global__ __launch_bounds__(256) void finalize_kernel(
    const float* __restrict__ posdis, const float* __restrict__ pose,
    const float* __restrict__ rowsum, const int* __restrict__ labels,
    const float* __restrict__ bias, float* __restrict__ out)
{
    int t = threadIdx.x;
    double sl = 0.0, sp = 0.0, sp2 = 0.0;
    for (int r = t; r < N_ROWS; r += 256) {
        float pd = posdis[r];                 // bf16-path label term (matches rowsum)
        float p  = pose[r] + bias[labels[r]]; // exact-path pos_metric
        float num = __expf(p);
        float den = rowsum[r] - __expf(pd) + num;
        sl  += (double)(logf(den) - p);
        sp  += (double)p;
        sp2 += (double)p * (double)p;
    }
    #pragma unroll
    for (int m = 1; m < 64; m <<= 1) {
        sl  += __shfl_xor(sl,  m, 64);
        sp  += __shfl_xor(sp,  m, 64);
        sp2 += __shfl_xor(sp2, m, 64);
    }
    __shared__ double sh[3][4];
    int w = t >> 6, lane = t & 63;
    if (lane == 0) { sh[0][w] = sl; sh[1][w] = sp; sh[2][w] = sp2; }
    __syncthreads();
    if (t == 0) {
        sl  = sh[0][0] + sh[0][1] + sh[0][2] + sh[0][3];
        sp  = sh[1][0] + sh[1][1] + sh[1][2] + sh[1][3];
        sp2 = sh[2][0] + sh[2][1] + sh[2][2] + sh[2][3];
        const double N = (double)N_ROWS;
        double mean = sp / N;
        double var  = (sp2 - N * mean * mean) / (N - 1.0);
        double loss = sl / N + var;
        out[0] = (float)loss;
        out[1] = (float)var;
    }
}

extern "C" void kernel_launch(void* const* d_in, const int* in_sizes, int n_in,
                              void* d_out, int out_size, void* d_ws, size_t ws_size,
                              hipStream_t stream) {
    const float* features = (const float*)d_in[0];
    const int*   labels   = (const int*)d_in[1];
    const float* centers  = (const float*)d_in[2];
    const float* bias     = (const float*)d_in[3];
    float* out = (float*)d_out;
    char* ws = (char*)d_ws;

    // Workspace layout (16B aligned), ~19.1 MB total.
    u16*   fb     = (u16*)(ws);                 // 8192*512*2  = 8388608
    u16*   cb     = (u16*)(ws + 8388608);       // 10240*512*2 = 10485760
    float* f2     = (float*)(ws + 18874368);    // 8192*4
    float* c2     = (float*)(ws + 18907136);    // 10240*4
    float* rowsum = (float*)(ws + 18948096);    // 8192*4
    float* posdis = (float*)(ws + 18980864);    // 8192*4
    float* pose   = (float*)(ws + 19013632);    // 8192*4

    hipMemsetAsync(rowsum, 0, N_ROWS * sizeof(float), stream);

    hipLaunchKernelGGL(norm_rows_kernel, dim3(N_ROWS / 4), dim3(256), 0, stream,
                       features, fb, f2, N_ROWS, N_ROWS);
    hipLaunchKernelGGL(norm_rows_kernel, dim3(C_PAD / 4), dim3(256), 0, stream,
                       centers, cb, c2, C_REAL, C_PAD);
    hipLaunchKernelGGL(pos_exact_kernel, dim3(N_ROWS / 4), dim3(256), 0, stream,
                       features, centers, labels, pose);

    hipFuncSetAttribute(reinterpret_cast<const void*>(gemm_kernel),
                        hipFuncAttributeMaxDynamicSharedMemorySize, SM_TOTAL);
    hipLaunchKernelGGL(gemm_kernel, dim3(C_PAD / BN, N_ROWS / BM), dim3(512), SM_TOTAL, stream,
                       fb, cb, f2, c2, labels, rowsum, posdis);

    hipLaunchKernelGGL(finalize_kernel, dim3(1), dim3(256), 0, stream,
                       posdis, pose, rowsum, labels, bias, out);
}